// Round 1
// baseline (148.696 us; speedup 1.0000x reference)
//
#include <hip/hip_runtime.h>
#include <stdint.h>
#include <stddef.h>

#define NTOK 4096
#define DDIM 1024

typedef __attribute__((ext_vector_type(4))) float f32x4;
typedef __attribute__((ext_vector_type(8))) short s16x8;
typedef __attribute__((ext_vector_type(4))) unsigned short u16x4;

__device__ __forceinline__ unsigned short f2bf(float f) {
  union { float f; unsigned u; } v; v.f = f;
  unsigned u = v.u + 0x7fffu + ((v.u >> 16) & 1u);
  return (unsigned short)(u >> 16);
}

// ---------- fp32 -> bf16 vectorized convert (G13) ----------
__global__ void convert_bf16_k(const float* __restrict__ in,
                               unsigned short* __restrict__ out, int n4) {
  int i = blockIdx.x * blockDim.x + threadIdx.x;
  int stride = gridDim.x * blockDim.x;
  const f32x4* in4 = (const f32x4*)in;
  u16x4* out4 = (u16x4*)out;
  for (; i < n4; i += stride) {
    f32x4 v = in4[i];
    u16x4 o;
    o[0] = f2bf(v[0]); o[1] = f2bf(v[1]); o[2] = f2bf(v[2]); o[3] = f2bf(v[3]);
    out4[i] = o;
  }
}

// ---------- transpose-convert M[1024][1024] fp32 -> Mt bf16 (Mt[r][l] = M[l][r]) ----------
__global__ void transpose_bf16_k(const float* __restrict__ M,
                                 unsigned short* __restrict__ Mt) {
  __shared__ unsigned short tile[32][33];
  int tx = threadIdx.x, ty = threadIdx.y;
  int bx = blockIdx.x, by = blockIdx.y;
  int x = bx * 32 + tx;
  for (int i = ty; i < 32; i += 8)
    tile[i][tx] = f2bf(M[(size_t)(by * 32 + i) * DDIM + x]);
  __syncthreads();
  int ox = by * 32 + tx;
  for (int i = ty; i < 32; i += 8)
    Mt[(size_t)(bx * 32 + i) * DDIM + ox] = tile[tx][i];
}

// ---------- lin term: out[row] = dot(x[row], w) + b0 (+ b1) ----------
__global__ void lin_k(const float* __restrict__ x, const float* __restrict__ w,
                      const float* __restrict__ b0, const float* __restrict__ b1,
                      float* __restrict__ out) {
  int wv = threadIdx.x >> 6, lane = threadIdx.x & 63;
  int row = blockIdx.x * 4 + wv;
  const f32x4* xr = (const f32x4*)(x + (size_t)row * DDIM);
  const f32x4* w4 = (const f32x4*)w;
  float s = 0.f;
  for (int j = lane; j < DDIM / 4; j += 64) {
    f32x4 a = xr[j], c = w4[j];
    s += a[0] * c[0] + a[1] * c[1] + a[2] * c[2] + a[3] * c[3];
  }
#pragma unroll
  for (int off = 32; off; off >>= 1) s += __shfl_down(s, off);
  if (lane == 0) out[row] = s + b0[0] + (b1 ? b1[0] : 0.f);
}

// ---------- detect mask element width: 1 (byte/bool) vs 4 (int32) ----------
// If the buffer is int32 0/1, every byte at (i%4)!=0 is zero; random bools are not.
__global__ void detect_mask_k(const unsigned char* __restrict__ m, int* __restrict__ flag) {
  __shared__ int f;
  if (threadIdx.x == 0) f = 0;
  __syncthreads();
  int any = 0;
  for (int i = threadIdx.x; i < 4096; i += 256)
    if ((i & 3) && m[i]) any = 1;
  if (any) atomicOr(&f, 1);
  __syncthreads();
  if (threadIdx.x == 0) *flag = f;  // 1 => byte mask, 0 => int32 mask
}

// ---------- m97-structure BT GEMM: C[M][N] = A[M][K] * B[N][K]^T (bf16 in, fp32 acc) ----------
__device__ __forceinline__ void gload_lds16(const void* g, void* l) {
  __builtin_amdgcn_global_load_lds(
      (const __attribute__((address_space(1))) void*)g,
      (__attribute__((address_space(3))) void*)l, 16, 0, 0);
}

template <int EPI>
__launch_bounds__(256, 2)
__global__ void gemm_bt_k(const unsigned short* __restrict__ A,
                          const unsigned short* __restrict__ B,
                          int K, int ldc,
                          unsigned short* __restrict__ Cb,          // EPI==0 output (bf16)
                          const float* __restrict__ linl,
                          const float* __restrict__ linr,
                          const void* __restrict__ mask,
                          const int* __restrict__ mflag,
                          float* __restrict__ scores,
                          float* __restrict__ xout) {
  __shared__ unsigned short As[128 * 64];
  __shared__ unsigned short Bs[128 * 64];
  const int bi = blockIdx.y, bj = blockIdx.x;
  const int t = threadIdx.x;
  const int wv = t >> 6, lane = t & 63;
  const int wr = wv >> 1, wc = wv & 1;
  const int l15 = lane & 15, l16 = lane >> 4;

  f32x4 acc[4][4] = {};

  // staging: each wave fills rows [wv*32, wv*32+32) of both tiles; 4 insts x 1KB each.
  // global_load_lds writes LDS base + lane*16B -> row = base_row + lane/8, k-slot = (lane&7)*8
  const int srow = wv * 32 + (lane >> 3);
  const int sk = (lane & 7) * 8;
  const unsigned short* Ag = A + (size_t)(bi * 128 + srow) * K + sk;
  const unsigned short* Bg = B + (size_t)(bj * 128 + srow) * K + sk;

  for (int k0 = 0; k0 < K; k0 += 64) {
#pragma unroll
    for (int i = 0; i < 4; ++i) {
      gload_lds16(Ag + (size_t)i * 8 * K + k0, As + (wv * 32 + i * 8) * 64);
      gload_lds16(Bg + (size_t)i * 8 * K + k0, Bs + (wv * 32 + i * 8) * 64);
    }
    asm volatile("s_waitcnt vmcnt(0)" ::: "memory");
    __syncthreads();

#pragma unroll
    for (int kk = 0; kk < 2; ++kk) {
      s16x8 af[4], bfr[4];
#pragma unroll
      for (int m = 0; m < 4; ++m)
        af[m] = *(const s16x8*)(As + (wr * 64 + m * 16 + l15) * 64 + kk * 32 + l16 * 8);
#pragma unroll
      for (int n = 0; n < 4; ++n)
        bfr[n] = *(const s16x8*)(Bs + (wc * 64 + n * 16 + l15) * 64 + kk * 32 + l16 * 8);
#pragma unroll
      for (int m = 0; m < 4; ++m)
#pragma unroll
        for (int n = 0; n < 4; ++n)
          acc[m][n] = __builtin_amdgcn_mfma_f32_16x16x32_bf16(af[m], bfr[n], acc[m][n], 0, 0, 0);
    }
    __syncthreads();
  }

  // C/D layout (m89-verified): col = lane&15, row = 4*(lane>>4) + reg
  if (EPI == 0) {
#pragma unroll
    for (int m = 0; m < 4; ++m) {
      int row0 = bi * 128 + wr * 64 + m * 16 + 4 * l16;
#pragma unroll
      for (int n = 0; n < 4; ++n) {
        int col = bj * 128 + wc * 64 + n * 16 + l15;
#pragma unroll
        for (int r = 0; r < 4; ++r)
          Cb[(size_t)(row0 + r) * ldc + col] = f2bf(acc[m][n][r]);
      }
    }
  } else {
    const int mf = *mflag;
#pragma unroll
    for (int m = 0; m < 4; ++m) {
      int row0 = bi * 128 + wr * 64 + m * 16 + 4 * l16;
#pragma unroll
      for (int r = 0; r < 4; ++r) {
        int row = row0 + r;
        float ll = linl[row];
#pragma unroll
        for (int n = 0; n < 4; ++n) {
          int col = bj * 128 + wc * 64 + n * 16 + l15;
          float v = acc[m][n][r] + ll + linr[col];
          v = v > 0.f ? v : 0.f;
          size_t idx = (size_t)row * (size_t)ldc + col;
          xout[idx] = v;
          int mk = mf ? (int)((const unsigned char*)mask)[idx]
                      : ((const int*)mask)[idx];
          scores[idx] = mk ? v : 0.f;
        }
      }
    }
  }
}

extern "C" void kernel_launch(void* const* d_in, const int* in_sizes, int n_in,
                              void* d_out, int out_size, void* d_ws, size_t ws_size,
                              hipStream_t stream) {
  const float* x_l    = (const float*)d_in[0];
  const float* x_r    = (const float*)d_in[1];
  const void*  maskp  = (const void*)d_in[2];
  const float* matrix = (const float*)d_in[3];
  const float* bias   = (const float*)d_in[4];
  const float* wl     = (const float*)d_in[5];
  const float* bl     = (const float*)d_in[6];
  const float* wr     = (const float*)d_in[7];
  const float* br     = (const float*)d_in[8];

  // workspace layout (bf16 elements are 2B)
  unsigned short* XLb = (unsigned short*)d_ws;                 // 8 MB
  unsigned short* XRb = XLb + (size_t)NTOK * DDIM;             // 8 MB
  unsigned short* XMb = XRb + (size_t)NTOK * DDIM;             // 8 MB
  unsigned short* Mtb = XMb + (size_t)NTOK * DDIM;             // 2 MB
  float* lin_l = (float*)(Mtb + (size_t)DDIM * DDIM);          // 16 KB
  float* lin_r = lin_l + NTOK;                                 // 16 KB
  int* mflag = (int*)(lin_r + NTOK);

  float* scores = (float*)d_out;
  float* xout = scores + (size_t)NTOK * NTOK;

  convert_bf16_k<<<1024, 256, 0, stream>>>(x_l, XLb, NTOK * DDIM / 4);
  convert_bf16_k<<<1024, 256, 0, stream>>>(x_r, XRb, NTOK * DDIM / 4);
  transpose_bf16_k<<<dim3(32, 32), dim3(32, 8), 0, stream>>>(matrix, Mtb);
  lin_k<<<NTOK / 4, 256, 0, stream>>>(x_l, wl, bl, bias, lin_l);
  lin_k<<<NTOK / 4, 256, 0, stream>>>(x_r, wr, br, nullptr, lin_r);
  detect_mask_k<<<1, 256, 0, stream>>>((const unsigned char*)maskp, mflag);

  // GEMM1: XM[4096][1024] = XLb[4096][1024] * Mtb[1024][1024]^T  (i.e. x_l @ M)
  gemm_bt_k<0><<<dim3(DDIM / 128, NTOK / 128), 256, 0, stream>>>(
      XLb, Mtb, DDIM, DDIM, XMb,
      nullptr, nullptr, nullptr, nullptr, nullptr, nullptr);

  // GEMM2 + epilogue: x = relu(XM @ XR^T + lin_l + lin_r^T), scores = mask ? x : 0
  gemm_bt_k<1><<<dim3(NTOK / 128, NTOK / 128), 256, 0, stream>>>(
      XMb, XRb, DDIM, NTOK, nullptr,
      lin_l, lin_r, maskp, mflag, scores, xout);
}

// Round 2
// 140.031 us; speedup vs baseline: 1.0619x; 1.0619x over previous
//
#include <hip/hip_runtime.h>
#include <stdint.h>
#include <stddef.h>

#define NTOK 4096
#define DDIM 1024

typedef __attribute__((ext_vector_type(4))) float f32x4;
typedef __attribute__((ext_vector_type(8))) short s16x8;
typedef __attribute__((ext_vector_type(4))) unsigned short u16x4;

__device__ __forceinline__ unsigned short f2bf(float f) {
  union { float f; unsigned u; } v; v.f = f;
  unsigned u = v.u + 0x7fffu + ((v.u >> 16) & 1u);
  return (unsigned short)(u >> 16);
}

__device__ __forceinline__ void gload_lds16(const void* g, void* l) {
  __builtin_amdgcn_global_load_lds(
      (const __attribute__((address_space(1))) void*)g,
      (__attribute__((address_space(3))) void*)l, 16, 0, 0);
}

// ---------- fused fp32->bf16 convert + lin dot (one pass over x) ----------
__global__ void convlin_k(const float* __restrict__ x, const float* __restrict__ w,
                          const float* __restrict__ b0, const float* __restrict__ b1,
                          unsigned short* __restrict__ xb, float* __restrict__ lin) {
  int wv = threadIdx.x >> 6, lane = threadIdx.x & 63;
  int row = blockIdx.x * 4 + wv;
  const f32x4* xr = (const f32x4*)(x + (size_t)row * DDIM);
  const f32x4* w4 = (const f32x4*)w;
  u16x4* xb4 = (u16x4*)(xb + (size_t)row * DDIM);
  float s = 0.f;
  for (int j = lane; j < DDIM / 4; j += 64) {
    f32x4 a = xr[j], c = w4[j];
    s += a[0] * c[0] + a[1] * c[1] + a[2] * c[2] + a[3] * c[3];
    u16x4 o;
    o[0] = f2bf(a[0]); o[1] = f2bf(a[1]); o[2] = f2bf(a[2]); o[3] = f2bf(a[3]);
    xb4[j] = o;
  }
#pragma unroll
  for (int off = 32; off; off >>= 1) s += __shfl_down(s, off);
  if (lane == 0) lin[row] = s + b0[0] + (b1 ? b1[0] : 0.f);
}

// ---------- transpose-convert M[1024][1024] fp32 -> Mt bf16 ----------
__global__ void transpose_bf16_k(const float* __restrict__ M,
                                 unsigned short* __restrict__ Mt) {
  __shared__ unsigned short tile[32][33];
  int tx = threadIdx.x, ty = threadIdx.y;
  int bx = blockIdx.x, by = blockIdx.y;
  int x = bx * 32 + tx;
  for (int i = ty; i < 32; i += 8)
    tile[i][tx] = f2bf(M[(size_t)(by * 32 + i) * DDIM + x]);
  __syncthreads();
  int ox = by * 32 + tx;
  for (int i = ty; i < 32; i += 8)
    Mt[(size_t)(bx * 32 + i) * DDIM + ox] = tile[tx][i];
}

// ---------- detect mask element width ----------
__global__ void detect_mask_k(const unsigned char* __restrict__ m, int* __restrict__ flag) {
  __shared__ int f;
  if (threadIdx.x == 0) f = 0;
  __syncthreads();
  int any = 0;
  for (int i = threadIdx.x; i < 4096; i += 256)
    if ((i & 3) && m[i]) any = 1;
  if (any) atomicOr(&f, 1);
  __syncthreads();
  if (threadIdx.x == 0) *flag = f;  // 1 => byte mask, 0 => int32 mask
}

// ---------- m97-structure 128x128 BT GEMM (kept for GEMM1) ----------
template <int EPI>
__launch_bounds__(256, 2)
__global__ void gemm_bt_k(const unsigned short* __restrict__ A,
                          const unsigned short* __restrict__ B,
                          int K, int ldc,
                          unsigned short* __restrict__ Cb) {
  __shared__ unsigned short As[128 * 64];
  __shared__ unsigned short Bs[128 * 64];
  const int bi = blockIdx.y, bj = blockIdx.x;
  const int t = threadIdx.x;
  const int wv = t >> 6, lane = t & 63;
  const int wr = wv >> 1, wc = wv & 1;
  const int l15 = lane & 15, l16 = lane >> 4;

  f32x4 acc[4][4] = {};

  const int srow = wv * 32 + (lane >> 3);
  const int sk = (lane & 7) * 8;
  const unsigned short* Ag = A + (size_t)(bi * 128 + srow) * K + sk;
  const unsigned short* Bg = B + (size_t)(bj * 128 + srow) * K + sk;

  for (int k0 = 0; k0 < K; k0 += 64) {
#pragma unroll
    for (int i = 0; i < 4; ++i) {
      gload_lds16(Ag + (size_t)i * 8 * K + k0, As + (wv * 32 + i * 8) * 64);
      gload_lds16(Bg + (size_t)i * 8 * K + k0, Bs + (wv * 32 + i * 8) * 64);
    }
    asm volatile("s_waitcnt vmcnt(0)" ::: "memory");
    __syncthreads();

#pragma unroll
    for (int kk = 0; kk < 2; ++kk) {
      s16x8 af[4], bfr[4];
#pragma unroll
      for (int m = 0; m < 4; ++m)
        af[m] = *(const s16x8*)(As + (wr * 64 + m * 16 + l15) * 64 + kk * 32 + l16 * 8);
#pragma unroll
      for (int n = 0; n < 4; ++n)
        bfr[n] = *(const s16x8*)(Bs + (wc * 64 + n * 16 + l15) * 64 + kk * 32 + l16 * 8);
#pragma unroll
      for (int m = 0; m < 4; ++m)
#pragma unroll
        for (int n = 0; n < 4; ++n)
          acc[m][n] = __builtin_amdgcn_mfma_f32_16x16x32_bf16(af[m], bfr[n], acc[m][n], 0, 0, 0);
    }
    __syncthreads();
  }

#pragma unroll
  for (int m = 0; m < 4; ++m) {
    int row0 = bi * 128 + wr * 64 + m * 16 + 4 * l16;
#pragma unroll
    for (int n = 0; n < 4; ++n) {
      int col = bj * 128 + wc * 64 + n * 16 + l15;
#pragma unroll
      for (int r = 0; r < 4; ++r)
        Cb[(size_t)(row0 + r) * ldc + col] = f2bf(acc[m][n][r]);
    }
  }
}

// ---------- 256x256 8-phase GEMM2 + fused epilogue ----------
// C = A[4096][1024] * B[4096][1024]^T; x = relu(C + linl + linr^T);
// scores = mask ? x : 0.   T2 swizzle + counted vmcnt + setprio.

#define STAGE_HALF(BUF, AB, H, GBASE, K0)                                        \
  {                                                                              \
    unsigned short* lb = &lds[BUF][AB][H][0][0] + wid * 512;                     \
    const unsigned short* g0 =                                                   \
        (GBASE) + (size_t)((H)*128 + srow0) * 1024 + (K0) + swslot * 8;          \
    gload_lds16(g0, lb);                                                         \
    gload_lds16(g0 + (size_t)64 * 1024, lb + 4096);                              \
  }

#define PHASE(QM, QN, SAB, SH, DOSTG, DOVM)                                      \
  {                                                                              \
    s16x8 a_[4][2], b_[2][2];                                                    \
    _Pragma("unroll") for (int m = 0; m < 4; ++m) {                              \
      _Pragma("unroll") for (int kk = 0; kk < 2; ++kk)                           \
          a_[m][kk] = *(const s16x8*)&lds[cur][0][QM][wr2 * 64 + m * 16 + l15]   \
                                         [(((kk << 2) | l16) ^ xm) << 3];        \
    }                                                                            \
    _Pragma("unroll") for (int n = 0; n < 2; ++n) {                              \
      _Pragma("unroll") for (int kk = 0; kk < 2; ++kk)                           \
          b_[n][kk] = *(const s16x8*)&lds[cur][1][QN][wc2 * 32 + n * 16 + l15]   \
                                         [(((kk << 2) | l16) ^ xm) << 3];        \
    }                                                                            \
    if (DOSTG) {                                                                 \
      if (SAB) { STAGE_HALF(nxt, 1, SH, Bbase, k0n) }                            \
      else     { STAGE_HALF(nxt, 0, SH, Abase, k0n) }                            \
    }                                                                            \
    __builtin_amdgcn_s_barrier();                                                \
    __builtin_amdgcn_s_setprio(1);                                               \
    _Pragma("unroll") for (int kk = 0; kk < 2; ++kk) {                           \
      _Pragma("unroll") for (int m = 0; m < 4; ++m) {                            \
        _Pragma("unroll") for (int n = 0; n < 2; ++n)                            \
            acc[QM][QN][m][n] = __builtin_amdgcn_mfma_f32_16x16x32_bf16(         \
                a_[m][kk], b_[n][kk], acc[QM][QN][m][n], 0, 0, 0);               \
      }                                                                          \
    }                                                                            \
    __builtin_amdgcn_s_setprio(0);                                               \
    if (DOVM) asm volatile("s_waitcnt vmcnt(4)" ::: "memory");                   \
    __builtin_amdgcn_s_barrier();                                                \
  }

__launch_bounds__(512, 2)
__global__ void gemm256_k(const unsigned short* __restrict__ A,
                          const unsigned short* __restrict__ B,
                          const float* __restrict__ linl,
                          const float* __restrict__ linr,
                          const void* __restrict__ mask,
                          const int* __restrict__ mflag,
                          float* __restrict__ scores,
                          float* __restrict__ xout) {
  // [buf][A/B][half][row][k] : 2*2*2*128*64*2B = 128 KiB
  __shared__ unsigned short lds[2][2][2][128][64];
  const int bi = blockIdx.y, bj = blockIdx.x;
  const int tid = threadIdx.x;
  const int wid = tid >> 6, lane = tid & 63;
  const int wr2 = wid >> 2, wc2 = wid & 3;  // 2 (M) x 4 (N) waves per quadrant
  const int l15 = lane & 15, l16 = lane >> 4;
  const int xm = lane & 7;  // read-side swizzle key (row&7 == l15&7)

  // staging geometry: inst j: linear LDS byte = j*8192 + tid*16
  const int srow0 = tid >> 3;
  const int swslot = (tid & 7) ^ (srow0 & 7);  // pre-swizzled global k-slot

  const unsigned short* Abase = A + (size_t)(bi * 256) * 1024;
  const unsigned short* Bbase = B + (size_t)(bj * 256) * 1024;

  f32x4 acc[2][2][4][2] = {};  // [qm][qn][m][n]

  // prologue: stage tile 0 (order A0,B0,A1,B1), retire first two halves
  STAGE_HALF(0, 0, 0, Abase, 0)
  STAGE_HALF(0, 1, 0, Bbase, 0)
  STAGE_HALF(0, 0, 1, Abase, 0)
  STAGE_HALF(0, 1, 1, Bbase, 0)
  asm volatile("s_waitcnt vmcnt(4)" ::: "memory");
  __builtin_amdgcn_s_barrier();

  const int nt = 1024 / 64;  // 16
  for (int t = 0; t < nt - 1; ++t) {
    const int cur = t & 1, nxt = cur ^ 1;
    const int k0n = (t + 1) * 64;
    PHASE(0, 0, 0, 0, 1, 1)  // compute quad (0,0); stage A-h0(t+1)
    PHASE(1, 0, 1, 0, 1, 1)  // compute quad (1,0); stage B-h0(t+1)
    PHASE(1, 1, 0, 1, 1, 1)  // compute quad (1,1); stage A-h1(t+1)
    PHASE(0, 1, 1, 1, 1, 1)  // compute quad (0,1); stage B-h1(t+1)
  }
  {
    const int cur = (nt - 1) & 1, nxt = cur ^ 1;
    const int k0n = 0;
    (void)nxt; (void)k0n;
    asm volatile("s_waitcnt vmcnt(0)" ::: "memory");
    __builtin_amdgcn_s_barrier();
    PHASE(0, 0, 0, 0, 0, 0)
    PHASE(1, 0, 0, 0, 0, 0)
    PHASE(1, 1, 0, 0, 0, 0)
    PHASE(0, 1, 0, 0, 0, 0)
  }

  // epilogue: relu(C + linl + linr^T), mask select, write both outputs
  const int mf = *mflag;
#pragma unroll
  for (int qm = 0; qm < 2; ++qm) {
#pragma unroll
    for (int m = 0; m < 4; ++m) {
#pragma unroll
      for (int r = 0; r < 4; ++r) {
        int row = bi * 256 + qm * 128 + wr2 * 64 + m * 16 + l16 * 4 + r;
        float ll = linl[row];
#pragma unroll
        for (int qn = 0; qn < 2; ++qn) {
#pragma unroll
          for (int n = 0; n < 2; ++n) {
            int col = bj * 256 + qn * 128 + wc2 * 32 + n * 16 + l15;
            float v = acc[qm][qn][m][n][r] + ll + linr[col];
            v = v > 0.f ? v : 0.f;
            size_t idx = (size_t)row * NTOK + col;
            xout[idx] = v;
            int mk = mf ? (int)((const unsigned char*)mask)[idx]
                        : ((const int*)mask)[idx];
            scores[idx] = mk ? v : 0.f;
          }
        }
      }
    }
  }
}

extern "C" void kernel_launch(void* const* d_in, const int* in_sizes, int n_in,
                              void* d_out, int out_size, void* d_ws, size_t ws_size,
                              hipStream_t stream) {
  const float* x_l    = (const float*)d_in[0];
  const float* x_r    = (const float*)d_in[1];
  const void*  maskp  = (const void*)d_in[2];
  const float* matrix = (const float*)d_in[3];
  const float* bias   = (const float*)d_in[4];
  const float* wl     = (const float*)d_in[5];
  const float* bl     = (const float*)d_in[6];
  const float* wr     = (const float*)d_in[7];
  const float* br     = (const float*)d_in[8];

  unsigned short* XLb = (unsigned short*)d_ws;
  unsigned short* XRb = XLb + (size_t)NTOK * DDIM;
  unsigned short* XMb = XRb + (size_t)NTOK * DDIM;
  unsigned short* Mtb = XMb + (size_t)NTOK * DDIM;
  float* lin_l = (float*)(Mtb + (size_t)DDIM * DDIM);
  float* lin_r = lin_l + NTOK;
  int* mflag = (int*)(lin_r + NTOK);

  float* scores = (float*)d_out;
  float* xout = scores + (size_t)NTOK * NTOK;

  convlin_k<<<NTOK / 4, 256, 0, stream>>>(x_l, wl, bl, bias, XLb, lin_l);
  convlin_k<<<NTOK / 4, 256, 0, stream>>>(x_r, wr, br, nullptr, XRb, lin_r);
  transpose_bf16_k<<<dim3(32, 32), dim3(32, 8), 0, stream>>>(matrix, Mtb);
  detect_mask_k<<<1, 256, 0, stream>>>((const unsigned char*)maskp, mflag);

  // GEMM1: XM = x_l @ M  (bf16 out)
  gemm_bt_k<0><<<dim3(DDIM / 128, NTOK / 128), 256, 0, stream>>>(
      XLb, Mtb, DDIM, DDIM, XMb);

  // GEMM2 (8-phase 256^2) + epilogue
  gemm256_k<<<dim3(NTOK / 256, NTOK / 256), 512, 0, stream>>>(
      XMb, XRb, lin_l, lin_r, maskp, mflag, scores, xout);
}

// Round 3
// 132.561 us; speedup vs baseline: 1.1217x; 1.0564x over previous
//
#include <hip/hip_runtime.h>
#include <stdint.h>
#include <stddef.h>

#define NTOK 4096
#define DDIM 1024

typedef __attribute__((ext_vector_type(4))) float f32x4;
typedef __attribute__((ext_vector_type(8))) short s16x8;
typedef __attribute__((ext_vector_type(4))) unsigned short u16x4;

__device__ __forceinline__ unsigned short f2bf(float f) {
  union { float f; unsigned u; } v; v.f = f;
  unsigned u = v.u + 0x7fffu + ((v.u >> 16) & 1u);
  return (unsigned short)(u >> 16);
}

__device__ __forceinline__ void gload_lds16(const void* g, void* l) {
  __builtin_amdgcn_global_load_lds(
      (const __attribute__((address_space(1))) void*)g,
      (__attribute__((address_space(3))) void*)l, 16, 0, 0);
}

#define VMWAIT(N) asm volatile("s_waitcnt vmcnt(" #N ")" ::: "memory")

// ---------- fused fp32->bf16 convert + lin dot (one pass over x) ----------
__global__ void convlin_k(const float* __restrict__ x, const float* __restrict__ w,
                          const float* __restrict__ b0, const float* __restrict__ b1,
                          unsigned short* __restrict__ xb, float* __restrict__ lin) {
  int wv = threadIdx.x >> 6, lane = threadIdx.x & 63;
  int row = blockIdx.x * 4 + wv;
  const f32x4* xr = (const f32x4*)(x + (size_t)row * DDIM);
  const f32x4* w4 = (const f32x4*)w;
  u16x4* xb4 = (u16x4*)(xb + (size_t)row * DDIM);
  float s = 0.f;
  for (int j = lane; j < DDIM / 4; j += 64) {
    f32x4 a = xr[j], c = w4[j];
    s += a[0] * c[0] + a[1] * c[1] + a[2] * c[2] + a[3] * c[3];
    u16x4 o;
    o[0] = f2bf(a[0]); o[1] = f2bf(a[1]); o[2] = f2bf(a[2]); o[3] = f2bf(a[3]);
    xb4[j] = o;
  }
#pragma unroll
  for (int off = 32; off; off >>= 1) s += __shfl_down(s, off);
  if (lane == 0) lin[row] = s + b0[0] + (b1 ? b1[0] : 0.f);
}

// ---------- transpose-convert M[1024][1024] fp32 -> Mt bf16 ----------
__global__ void transpose_bf16_k(const float* __restrict__ M,
                                 unsigned short* __restrict__ Mt) {
  __shared__ unsigned short tile[32][33];
  int tx = threadIdx.x, ty = threadIdx.y;
  int bx = blockIdx.x, by = blockIdx.y;
  int x = bx * 32 + tx;
  for (int i = ty; i < 32; i += 8)
    tile[i][tx] = f2bf(M[(size_t)(by * 32 + i) * DDIM + x]);
  __syncthreads();
  int ox = by * 32 + tx;
  for (int i = ty; i < 32; i += 8)
    Mt[(size_t)(bx * 32 + i) * DDIM + ox] = tile[tx][i];
}

// ---------- detect mask element width ----------
__global__ void detect_mask_k(const unsigned char* __restrict__ m, int* __restrict__ flag) {
  __shared__ int f;
  if (threadIdx.x == 0) f = 0;
  __syncthreads();
  int any = 0;
  for (int i = threadIdx.x; i < 4096; i += 256)
    if ((i & 3) && m[i]) any = 1;
  if (any) atomicOr(&f, 1);
  __syncthreads();
  if (threadIdx.x == 0) *flag = f;  // 1 => byte mask, 0 => int32 mask
}

// ---------- m97-structure 128x128 BT GEMM (GEMM1: XM = x_l @ M) ----------
__launch_bounds__(256, 2)
__global__ void gemm_bt_k(const unsigned short* __restrict__ A,
                          const unsigned short* __restrict__ B,
                          int K, int ldc,
                          unsigned short* __restrict__ Cb) {
  __shared__ unsigned short As[128 * 64];
  __shared__ unsigned short Bs[128 * 64];
  const int bi = blockIdx.y, bj = blockIdx.x;
  const int t = threadIdx.x;
  const int wv = t >> 6, lane = t & 63;
  const int wr = wv >> 1, wc = wv & 1;
  const int l15 = lane & 15, l16 = lane >> 4;

  f32x4 acc[4][4] = {};

  const int srow = wv * 32 + (lane >> 3);
  const int sk = (lane & 7) * 8;
  const unsigned short* Ag = A + (size_t)(bi * 128 + srow) * K + sk;
  const unsigned short* Bg = B + (size_t)(bj * 128 + srow) * K + sk;

  for (int k0 = 0; k0 < K; k0 += 64) {
#pragma unroll
    for (int i = 0; i < 4; ++i) {
      gload_lds16(Ag + (size_t)i * 8 * K + k0, As + (wv * 32 + i * 8) * 64);
      gload_lds16(Bg + (size_t)i * 8 * K + k0, Bs + (wv * 32 + i * 8) * 64);
    }
    asm volatile("s_waitcnt vmcnt(0)" ::: "memory");
    __syncthreads();

#pragma unroll
    for (int kk = 0; kk < 2; ++kk) {
      s16x8 af[4], bfr[4];
#pragma unroll
      for (int m = 0; m < 4; ++m)
        af[m] = *(const s16x8*)(As + (wr * 64 + m * 16 + l15) * 64 + kk * 32 + l16 * 8);
#pragma unroll
      for (int n = 0; n < 4; ++n)
        bfr[n] = *(const s16x8*)(Bs + (wc * 64 + n * 16 + l15) * 64 + kk * 32 + l16 * 8);
#pragma unroll
      for (int m = 0; m < 4; ++m)
#pragma unroll
        for (int n = 0; n < 4; ++n)
          acc[m][n] = __builtin_amdgcn_mfma_f32_16x16x32_bf16(af[m], bfr[n], acc[m][n], 0, 0, 0);
    }
    __syncthreads();
  }

#pragma unroll
  for (int m = 0; m < 4; ++m) {
    int row0 = bi * 128 + wr * 64 + m * 16 + 4 * l16;
#pragma unroll
    for (int n = 0; n < 4; ++n) {
      int col = bj * 128 + wc * 64 + n * 16 + l15;
#pragma unroll
      for (int r = 0; r < 4; ++r)
        Cb[(size_t)(row0 + r) * ldc + col] = f2bf(acc[m][n][r]);
    }
  }
}

// ---------- 256x256 GEMM2, m201-faithful waits + frag reuse ----------
// Phase order (0,0)->(1,0)->(1,1)->(0,1); loads: A0+B0 / A1 / B1 / A0.
// Stage order A0,B0,A1,B1 (next tile); vmcnt(4) at P1,P2,P4 => every half
// >=3 phases in flight, 4-8 loads outstanding, never drained mid-loop.

#define STAGE_HALF(BUF, AB, H, GBASE, K0)                                        \
  {                                                                              \
    unsigned short* lb = &lds[BUF][AB][H][0][0] + wid * 512;                     \
    const unsigned short* g0 =                                                   \
        (GBASE) + (size_t)((H)*128 + srow0) * 1024 + (K0) + swslot * 8;          \
    gload_lds16(g0, lb);                                                         \
    gload_lds16(g0 + (size_t)64 * 1024, lb + 4096);                              \
  }

#define PHASE(QM, QN, DO_LDA, DO_LDB, DOSTG, SAB, SH, WAITSTMT)                  \
  {                                                                              \
    if (DO_LDA) {                                                                \
      _Pragma("unroll") for (int m = 0; m < 4; ++m) {                            \
        _Pragma("unroll") for (int kk = 0; kk < 2; ++kk)                         \
            Areg[m][kk] = *(const s16x8*)&lds[cur][0][QM]                        \
                [wr2 * 64 + m * 16 + l15][(((kk << 2) | l16) ^ xm) << 3];        \
      }                                                                          \
    }                                                                            \
    if (DO_LDB) {                                                                \
      _Pragma("unroll") for (int n = 0; n < 2; ++n) {                            \
        _Pragma("unroll") for (int kk = 0; kk < 2; ++kk)                         \
            Breg[n][kk] = *(const s16x8*)&lds[cur][1][QN]                        \
                [wc2 * 32 + n * 16 + l15][(((kk << 2) | l16) ^ xm) << 3];        \
      }                                                                          \
    }                                                                            \
    if (DOSTG) {                                                                 \
      if (SAB) { STAGE_HALF(nxt, 1, SH, Bbase, k0n) }                            \
      else     { STAGE_HALF(nxt, 0, SH, Abase, k0n) }                            \
    }                                                                            \
    __builtin_amdgcn_s_barrier();                                                \
    __builtin_amdgcn_s_setprio(1);                                               \
    _Pragma("unroll") for (int kk = 0; kk < 2; ++kk) {                           \
      _Pragma("unroll") for (int m = 0; m < 4; ++m) {                            \
        _Pragma("unroll") for (int n = 0; n < 2; ++n)                            \
            acc[QM][QN][m][n] = __builtin_amdgcn_mfma_f32_16x16x32_bf16(         \
                Areg[m][kk], Breg[n][kk], acc[QM][QN][m][n], 0, 0, 0);           \
      }                                                                          \
    }                                                                            \
    __builtin_amdgcn_s_setprio(0);                                               \
    WAITSTMT                                                                     \
    __builtin_amdgcn_s_barrier();                                                \
  }

__launch_bounds__(512, 2)
__global__ void gemm256_k(const unsigned short* __restrict__ A,
                          const unsigned short* __restrict__ B,
                          const float* __restrict__ linl,
                          const float* __restrict__ linr,
                          const void* __restrict__ mask,
                          const int* __restrict__ mflag,
                          float* __restrict__ scores,
                          float* __restrict__ xout) {
  __shared__ unsigned short lds[2][2][2][128][64];  // 128 KiB
  // XCD-aware bijective swizzle (T1): 256 wgs, 8 XCDs, 32/XCD contiguous.
  const int lin = blockIdx.x;
  const int swz = (lin & 7) * 32 + (lin >> 3);
  const int bi = swz >> 4, bj = swz & 15;

  const int tid = threadIdx.x;
  const int wid = tid >> 6, lane = tid & 63;
  const int wr2 = wid >> 2, wc2 = wid & 3;  // 2(M) x 4(N) waves
  const int l15 = lane & 15, l16 = lane >> 4;
  const int xm = lane & 7;

  const int srow0 = tid >> 3;
  const int swslot = (tid & 7) ^ (srow0 & 7);

  const unsigned short* Abase = A + (size_t)(bi * 256) * 1024;
  const unsigned short* Bbase = B + (size_t)(bj * 256) * 1024;

  f32x4 acc[2][2][4][2] = {};
  s16x8 Areg[4][2], Breg[2][2];

  // prologue: tile 0 halves A0,B0,A1,B1; retire A0,B0, keep A1,B1 in flight
  STAGE_HALF(0, 0, 0, Abase, 0)
  STAGE_HALF(0, 1, 0, Bbase, 0)
  STAGE_HALF(0, 0, 1, Abase, 0)
  STAGE_HALF(0, 1, 1, Bbase, 0)
  VMWAIT(4);
  __builtin_amdgcn_s_barrier();

  for (int t = 0; t < 15; ++t) {
    const int cur = t & 1, nxt = cur ^ 1;
    const int k0n = (t + 1) * 64;
    PHASE(0, 0, 1, 1, 1, 0, 0, VMWAIT(4);)  // lds A0,B0; stage A0'; retire A1
    PHASE(1, 0, 1, 0, 1, 1, 0, VMWAIT(4);)  // lds A1;    stage B0'; retire B1
    PHASE(1, 1, 0, 1, 1, 0, 1, )            // lds B1;    stage A1'
    PHASE(0, 1, 1, 0, 1, 1, 1, VMWAIT(4);)  // lds A0;    stage B1'; retire A0',B0'
  }
  {  // last tile t=15: no staging; drain progressively
    const int cur = 1, nxt = 0, k0n = 0;
    (void)nxt; (void)k0n;
    PHASE(0, 0, 1, 1, 0, 0, 0, VMWAIT(2);)
    PHASE(1, 0, 1, 0, 0, 0, 0, VMWAIT(0);)
    PHASE(1, 1, 0, 1, 0, 0, 0, )
    PHASE(0, 1, 1, 0, 0, 0, 0, )
  }

  // epilogue: relu(C + linl + linr^T), mask select, nontemporal streaming writes
  const int mf = *mflag;
#pragma unroll
  for (int qm = 0; qm < 2; ++qm) {
#pragma unroll
    for (int m = 0; m < 4; ++m) {
#pragma unroll
      for (int r = 0; r < 4; ++r) {
        int row = bi * 256 + qm * 128 + wr2 * 64 + m * 16 + l16 * 4 + r;
        float ll = linl[row];
#pragma unroll
        for (int qn = 0; qn < 2; ++qn) {
#pragma unroll
          for (int n = 0; n < 2; ++n) {
            int col = bj * 256 + qn * 128 + wc2 * 32 + n * 16 + l15;
            float v = acc[qm][qn][m][n][r] + ll + linr[col];
            v = v > 0.f ? v : 0.f;
            size_t idx = (size_t)row * NTOK + col;
            int mk = mf ? (int)((const unsigned char*)mask)[idx]
                        : ((const int*)mask)[idx];
            __builtin_nontemporal_store(v, &xout[idx]);
            __builtin_nontemporal_store(mk ? v : 0.f, &scores[idx]);
          }
        }
      }
    }
  }
}

extern "C" void kernel_launch(void* const* d_in, const int* in_sizes, int n_in,
                              void* d_out, int out_size, void* d_ws, size_t ws_size,
                              hipStream_t stream) {
  const float* x_l    = (const float*)d_in[0];
  const float* x_r    = (const float*)d_in[1];
  const void*  maskp  = (const void*)d_in[2];
  const float* matrix = (const float*)d_in[3];
  const float* bias   = (const float*)d_in[4];
  const float* wl     = (const float*)d_in[5];
  const float* bl     = (const float*)d_in[6];
  const float* wr     = (const float*)d_in[7];
  const float* br     = (const float*)d_in[8];

  unsigned short* XLb = (unsigned short*)d_ws;
  unsigned short* XRb = XLb + (size_t)NTOK * DDIM;
  unsigned short* XMb = XRb + (size_t)NTOK * DDIM;
  unsigned short* Mtb = XMb + (size_t)NTOK * DDIM;
  float* lin_l = (float*)(Mtb + (size_t)DDIM * DDIM);
  float* lin_r = lin_l + NTOK;
  int* mflag = (int*)(lin_r + NTOK);

  float* scores = (float*)d_out;
  float* xout = scores + (size_t)NTOK * NTOK;

  convlin_k<<<NTOK / 4, 256, 0, stream>>>(x_l, wl, bl, bias, XLb, lin_l);
  convlin_k<<<NTOK / 4, 256, 0, stream>>>(x_r, wr, br, nullptr, XRb, lin_r);
  transpose_bf16_k<<<dim3(32, 32), dim3(32, 8), 0, stream>>>(matrix, Mtb);
  detect_mask_k<<<1, 256, 0, stream>>>((const unsigned char*)maskp, mflag);

  gemm_bt_k<<<dim3(DDIM / 128, NTOK / 128), 256, 0, stream>>>(
      XLb, Mtb, DDIM, DDIM, XMb);

  gemm256_k<<<256, 512, 0, stream>>>(
      XMb, XRb, lin_l, lin_r, maskp, mflag, scores, xout);
}

// Round 4
// 118.983 us; speedup vs baseline: 1.2497x; 1.1141x over previous
//
#include <hip/hip_runtime.h>
#include <stdint.h>
#include <stddef.h>

#define NTOK 4096
#define DDIM 1024

typedef __attribute__((ext_vector_type(4))) float f32x4;
typedef __attribute__((ext_vector_type(8))) short s16x8;
typedef __attribute__((ext_vector_type(4))) unsigned short u16x4;

__device__ __forceinline__ unsigned short f2bf(float f) {
  union { float f; unsigned u; } v; v.f = f;
  unsigned u = v.u + 0x7fffu + ((v.u >> 16) & 1u);
  return (unsigned short)(u >> 16);
}

__device__ __forceinline__ void gload_lds16(const void* g, void* l) {
  __builtin_amdgcn_global_load_lds(
      (const __attribute__((address_space(1))) void*)g,
      (__attribute__((address_space(3))) void*)l, 16, 0, 0);
}

// ---------- fused fp32->bf16 convert + lin dot ----------
__global__ void convlin_k(const float* __restrict__ x, const float* __restrict__ w,
                          const float* __restrict__ b0, const float* __restrict__ b1,
                          unsigned short* __restrict__ xb, float* __restrict__ lin) {
  int wv = threadIdx.x >> 6, lane = threadIdx.x & 63;
  int row = blockIdx.x * 4 + wv;
  const f32x4* xr = (const f32x4*)(x + (size_t)row * DDIM);
  const f32x4* w4 = (const f32x4*)w;
  u16x4* xb4 = (u16x4*)(xb + (size_t)row * DDIM);
  float s = 0.f;
  for (int j = lane; j < DDIM / 4; j += 64) {
    f32x4 a = xr[j], c = w4[j];
    s += a[0] * c[0] + a[1] * c[1] + a[2] * c[2] + a[3] * c[3];
    u16x4 o;
    o[0] = f2bf(a[0]); o[1] = f2bf(a[1]); o[2] = f2bf(a[2]); o[3] = f2bf(a[3]);
    xb4[j] = o;
  }
#pragma unroll
  for (int off = 32; off; off >>= 1) s += __shfl_down(s, off);
  if (lane == 0) lin[row] = s + b0[0] + (b1 ? b1[0] : 0.f);
}

// ---------- transpose-convert M fp32 -> Mt bf16 ----------
__global__ void transpose_bf16_k(const float* __restrict__ M,
                                 unsigned short* __restrict__ Mt) {
  __shared__ unsigned short tile[32][33];
  int tx = threadIdx.x, ty = threadIdx.y;
  int bx = blockIdx.x, by = blockIdx.y;
  int x = bx * 32 + tx;
  for (int i = ty; i < 32; i += 8)
    tile[i][tx] = f2bf(M[(size_t)(by * 32 + i) * DDIM + x]);
  __syncthreads();
  int ox = by * 32 + tx;
  for (int i = ty; i < 32; i += 8)
    Mt[(size_t)(bx * 32 + i) * DDIM + ox] = tile[tx][i];
}

// ---------- detect mask element width ----------
__global__ void detect_mask_k(const unsigned char* __restrict__ m, int* __restrict__ flag) {
  __shared__ int f;
  if (threadIdx.x == 0) f = 0;
  __syncthreads();
  int any = 0;
  for (int i = threadIdx.x; i < 4096; i += 256)
    if ((i & 3) && m[i]) any = 1;
  if (any) atomicOr(&f, 1);
  __syncthreads();
  if (threadIdx.x == 0) *flag = f;  // 1 => byte mask, 0 => int32 mask
}

// ---------- double-buffered BT GEMM, 2+ blocks/CU for overlap ----------
// C[BM x BN] per block; A[M][K] * B[N][K]^T, bf16 in, fp32 acc.
// 8 waves as 2(M) x 4(N); wave tile (BM/2)x(BN/4); T2 both-sides swizzle.

template <int EPI, int BM, int BN, int NBJ>
__launch_bounds__(512, 4)
__global__ void gemm_db_k(const unsigned short* __restrict__ A,
                          const unsigned short* __restrict__ B,
                          int K, int ldc,
                          unsigned short* __restrict__ Cb,
                          const float* __restrict__ linl,
                          const float* __restrict__ linr,
                          const void* __restrict__ mask,
                          const int* __restrict__ mflag,
                          float* __restrict__ scores,
                          float* __restrict__ xout) {
  constexpr int MF = BM / 32;  // M-frags per wave (WM=2)
  constexpr int NF = BN / 64;  // N-frags per wave (WN=4)
  constexpr int AI = BM / 64;  // stage insts for A (8KB block-wide each)
  constexpr int BI = BN / 64;
  __shared__ unsigned short As[2][BM][64];
  __shared__ unsigned short Bs[2][BN][64];

  // XCD-chunked bijective swizzle (grid % 8 == 0 always here)
  const int lin = blockIdx.x;
  const int cpx = gridDim.x >> 3;
  const int swz = (lin & 7) * cpx + (lin >> 3);
  const int bi = swz / NBJ, bj = swz % NBJ;

  const int tid = threadIdx.x;
  const int wid = tid >> 6, lane = tid & 63;
  const int wr2 = wid >> 2, wc2 = wid & 3;
  const int l15 = lane & 15, l16 = lane >> 4;
  const int xm = lane & 7;

  // staging: inst j covers rows j*64..j*64+63; wave w writes rows 8w..8w+7.
  // LDS written linearly (base + lane*16B); global k-slot pre-swizzled.
  const int srow0 = tid >> 3;
  const int swslot = (tid & 7) ^ (srow0 & 7);
  const unsigned short* Ag = A + (size_t)(bi * BM + srow0) * K + swslot * 8;
  const unsigned short* Bg = B + (size_t)(bj * BN + srow0) * K + swslot * 8;

  f32x4 acc[MF][NF] = {};

#define STAGE_T(BUF, K0)                                                     \
  {                                                                          \
    _Pragma("unroll") for (int j = 0; j < AI; ++j)                           \
        gload_lds16(Ag + (size_t)(j * 64) * K + (K0),                        \
                    &As[BUF][0][0] + j * 4096 + wid * 512);                  \
    _Pragma("unroll") for (int j = 0; j < BI; ++j)                           \
        gload_lds16(Bg + (size_t)(j * 64) * K + (K0),                        \
                    &Bs[BUF][0][0] + j * 4096 + wid * 512);                  \
  }

  STAGE_T(0, 0)
  asm volatile("s_waitcnt vmcnt(0)" ::: "memory");
  __builtin_amdgcn_s_barrier();

  const int nt = K >> 6;
  for (int t = 0; t < nt; ++t) {
    const int cur = t & 1, nxt = cur ^ 1;
    if (t + 1 < nt) STAGE_T(nxt, (t + 1) * 64)  // prefetch overlaps compute
#pragma unroll
    for (int kk = 0; kk < 2; ++kk) {
      s16x8 Areg[MF], Breg[NF];
#pragma unroll
      for (int m = 0; m < MF; ++m)
        Areg[m] = *(const s16x8*)&As[cur][wr2 * (BM / 2) + m * 16 + l15]
                                     [(((kk << 2) | l16) ^ xm) << 3];
#pragma unroll
      for (int n = 0; n < NF; ++n)
        Breg[n] = *(const s16x8*)&Bs[cur][wc2 * (BN / 4) + n * 16 + l15]
                                     [(((kk << 2) | l16) ^ xm) << 3];
      __builtin_amdgcn_s_setprio(1);
#pragma unroll
      for (int m = 0; m < MF; ++m)
#pragma unroll
        for (int n = 0; n < NF; ++n)
          acc[m][n] = __builtin_amdgcn_mfma_f32_16x16x32_bf16(
              Areg[m], Breg[n], acc[m][n], 0, 0, 0);
      __builtin_amdgcn_s_setprio(0);
    }
    __builtin_amdgcn_sched_barrier(0);  // pin MFMA before the wait (rule #18)
    asm volatile("s_waitcnt vmcnt(0)" ::: "memory");
    __builtin_amdgcn_s_barrier();
  }

  // C/D layout: col = lane&15, row = 4*(lane>>4) + reg
  if (EPI == 0) {
#pragma unroll
    for (int m = 0; m < MF; ++m) {
      int row0 = bi * BM + wr2 * (BM / 2) + m * 16 + 4 * l16;
#pragma unroll
      for (int n = 0; n < NF; ++n) {
        int col = bj * BN + wc2 * (BN / 4) + n * 16 + l15;
#pragma unroll
        for (int r = 0; r < 4; ++r)
          Cb[(size_t)(row0 + r) * ldc + col] = f2bf(acc[m][n][r]);
      }
    }
  } else {
    const int mf = *mflag;
#pragma unroll
    for (int m = 0; m < MF; ++m) {
#pragma unroll
      for (int r = 0; r < 4; ++r) {
        int row = bi * BM + wr2 * (BM / 2) + m * 16 + 4 * l16 + r;
        float ll = linl[row];
#pragma unroll
        for (int n = 0; n < NF; ++n) {
          int col = bj * BN + wc2 * (BN / 4) + n * 16 + l15;
          float v = acc[m][n][r] + ll + linr[col];
          v = v > 0.f ? v : 0.f;
          size_t idx = (size_t)row * (size_t)ldc + col;
          xout[idx] = v;
          int mk = mf ? (int)((const unsigned char*)mask)[idx]
                      : ((const int*)mask)[idx];
          scores[idx] = mk ? v : 0.f;
        }
      }
    }
  }
#undef STAGE_T
}

extern "C" void kernel_launch(void* const* d_in, const int* in_sizes, int n_in,
                              void* d_out, int out_size, void* d_ws, size_t ws_size,
                              hipStream_t stream) {
  const float* x_l    = (const float*)d_in[0];
  const float* x_r    = (const float*)d_in[1];
  const void*  maskp  = (const void*)d_in[2];
  const float* matrix = (const float*)d_in[3];
  const float* bias   = (const float*)d_in[4];
  const float* wl     = (const float*)d_in[5];
  const float* bl     = (const float*)d_in[6];
  const float* wr     = (const float*)d_in[7];
  const float* br     = (const float*)d_in[8];

  unsigned short* XLb = (unsigned short*)d_ws;
  unsigned short* XRb = XLb + (size_t)NTOK * DDIM;
  unsigned short* XMb = XRb + (size_t)NTOK * DDIM;
  unsigned short* Mtb = XMb + (size_t)NTOK * DDIM;
  float* lin_l = (float*)(Mtb + (size_t)DDIM * DDIM);
  float* lin_r = lin_l + NTOK;
  int* mflag = (int*)(lin_r + NTOK);

  float* scores = (float*)d_out;
  float* xout = scores + (size_t)NTOK * NTOK;

  convlin_k<<<NTOK / 4, 256, 0, stream>>>(x_l, wl, bl, bias, XLb, lin_l);
  convlin_k<<<NTOK / 4, 256, 0, stream>>>(x_r, wr, br, nullptr, XRb, lin_r);
  transpose_bf16_k<<<dim3(32, 32), dim3(32, 8), 0, stream>>>(matrix, Mtb);
  detect_mask_k<<<1, 256, 0, stream>>>((const unsigned char*)maskp, mflag);

  // GEMM1: XM = x_l @ M   (64x128 tile, grid 512 -> 2-3 blocks/CU)
  gemm_db_k<0, 64, 128, 8><<<512, 512, 0, stream>>>(
      XLb, Mtb, DDIM, DDIM, XMb,
      nullptr, nullptr, nullptr, nullptr, nullptr, nullptr);

  // GEMM2 + epilogue (128x128 tile, grid 1024 -> 2 blocks/CU)
  gemm_db_k<1, 128, 128, 32><<<1024, 512, 0, stream>>>(
      XMb, XRb, DDIM, NTOK, nullptr,
      lin_l, lin_r, maskp, mflag, scores, xout);
}

// Round 5
// 93.647 us; speedup vs baseline: 1.5878x; 1.2706x over previous
//
#include <hip/hip_runtime.h>
#include <stdint.h>
#include <stddef.h>

#define NTOK 4096
#define DDIM 1024

typedef __attribute__((ext_vector_type(4))) float f32x4;
typedef __attribute__((ext_vector_type(8))) short s16x8;
typedef __attribute__((ext_vector_type(4))) unsigned short u16x4;

__device__ __forceinline__ unsigned short f2bf(float f) {
  union { float f; unsigned u; } v; v.f = f;
  unsigned u = v.u + 0x7fffu + ((v.u >> 16) & 1u);
  return (unsigned short)(u >> 16);
}

__device__ __forceinline__ void gload_lds16(const void* g, void* l) {
  __builtin_amdgcn_global_load_lds(
      (const __attribute__((address_space(1))) void*)g,
      (__attribute__((address_space(3))) void*)l, 16, 0, 0);
}

// ---------- fused fp32->bf16 convert + lin dot ----------
__global__ void convlin_k(const float* __restrict__ x, const float* __restrict__ w,
                          const float* __restrict__ b0, const float* __restrict__ b1,
                          unsigned short* __restrict__ xb, float* __restrict__ lin) {
  int wv = threadIdx.x >> 6, lane = threadIdx.x & 63;
  int row = blockIdx.x * 4 + wv;
  const f32x4* xr = (const f32x4*)(x + (size_t)row * DDIM);
  const f32x4* w4 = (const f32x4*)w;
  u16x4* xb4 = (u16x4*)(xb + (size_t)row * DDIM);
  float s = 0.f;
  for (int j = lane; j < DDIM / 4; j += 64) {
    f32x4 a = xr[j], c = w4[j];
    s += a[0] * c[0] + a[1] * c[1] + a[2] * c[2] + a[3] * c[3];
    u16x4 o;
    o[0] = f2bf(a[0]); o[1] = f2bf(a[1]); o[2] = f2bf(a[2]); o[3] = f2bf(a[3]);
    xb4[j] = o;
  }
#pragma unroll
  for (int off = 32; off; off >>= 1) s += __shfl_down(s, off);
  if (lane == 0) lin[row] = s + b0[0] + (b1 ? b1[0] : 0.f);
}

// ---------- transpose-convert M fp32 -> Mt bf16 ----------
__global__ void transpose_bf16_k(const float* __restrict__ M,
                                 unsigned short* __restrict__ Mt) {
  __shared__ unsigned short tile[32][33];
  int tx = threadIdx.x, ty = threadIdx.y;
  int bx = blockIdx.x, by = blockIdx.y;
  int x = bx * 32 + tx;
  for (int i = ty; i < 32; i += 8)
    tile[i][tx] = f2bf(M[(size_t)(by * 32 + i) * DDIM + x]);
  __syncthreads();
  int ox = by * 32 + tx;
  for (int i = ty; i < 32; i += 8)
    Mt[(size_t)(bx * 32 + i) * DDIM + ox] = tile[tx][i];
}

// ---------- detect mask element width ----------
__global__ void detect_mask_k(const unsigned char* __restrict__ m, int* __restrict__ flag) {
  __shared__ int f;
  if (threadIdx.x == 0) f = 0;
  __syncthreads();
  int any = 0;
  for (int i = threadIdx.x; i < 4096; i += 256)
    if ((i & 3) && m[i]) any = 1;
  if (any) atomicOr(&f, 1);
  __syncthreads();
  if (threadIdx.x == 0) *flag = f;  // 1 => byte mask, 0 => int32 mask
}

// ---------- double-buffered BT GEMM ----------
// C[BM x BN] per block; A[M][K] * B[N][K]^T, bf16 in, fp32 acc.
// 8 waves as 2(M) x 4(N); T2 both-sides swizzle; coalesced f32x4 epilogue.

template <int EPI, int BM, int BN, int NBJ>
__launch_bounds__(512, 4)
__global__ void gemm_db_k(const unsigned short* __restrict__ A,
                          const unsigned short* __restrict__ B,
                          int K, int ldc,
                          unsigned short* __restrict__ Cb,
                          const float* __restrict__ linl,
                          const float* __restrict__ linr,
                          const void* __restrict__ mask,
                          const int* __restrict__ mflag,
                          float* __restrict__ scores,
                          float* __restrict__ xout) {
  constexpr int MF = BM / 32;
  constexpr int NF = BN / 64;
  constexpr int AI = BM / 64;
  constexpr int BI = BN / 64;
  constexpr int SMEMB = (2 * BM * 64 + 2 * BN * 64) * 2;  // == BM*BN*4 at 128x128
  __shared__ __align__(16) unsigned char smem[SMEMB];
  unsigned short* Asb = (unsigned short*)smem;
  unsigned short* Bsb = Asb + 2 * BM * 64;

  const int lin = blockIdx.x;
  int bi, bj;
  if constexpr (EPI == 1) {
    // patch swizzle: 32 patches of 4(bi) x 8(bj) blocks -> 3MB L2 footprint
    const int xcd = lin & 7, s = lin >> 3;
    const int p = (s >> 5) * 8 + xcd;  // 0..31
    const int w = s & 31;
    bi = (p >> 2) * 4 + (w >> 3);
    bj = (p & 3) * 8 + (w & 7);
  } else {
    const int cpx = gridDim.x >> 3;
    const int swz = (lin & 7) * cpx + (lin >> 3);
    bi = swz / NBJ; bj = swz % NBJ;
  }

  const int tid = threadIdx.x;
  const int wid = tid >> 6, lane = tid & 63;
  const int wr2 = wid >> 2, wc2 = wid & 3;
  const int l15 = lane & 15, l16 = lane >> 4;
  const int xm = lane & 7;

  const int srow0 = tid >> 3;
  const int swslot = (tid & 7) ^ (srow0 & 7);
  const unsigned short* Ag = A + (size_t)(bi * BM + srow0) * K + swslot * 8;
  const unsigned short* Bg = B + (size_t)(bj * BN + srow0) * K + swslot * 8;

  f32x4 acc[MF][NF] = {};

#define STAGE_T(BUF, K0)                                                     \
  {                                                                          \
    _Pragma("unroll") for (int j = 0; j < AI; ++j)                           \
        gload_lds16(Ag + (size_t)(j * 64) * K + (K0),                        \
                    Asb + (BUF)*BM * 64 + j * 4096 + wid * 512);             \
    _Pragma("unroll") for (int j = 0; j < BI; ++j)                           \
        gload_lds16(Bg + (size_t)(j * 64) * K + (K0),                        \
                    Bsb + (BUF)*BN * 64 + j * 4096 + wid * 512);             \
  }

  STAGE_T(0, 0)
  asm volatile("s_waitcnt vmcnt(0)" ::: "memory");
  __builtin_amdgcn_s_barrier();

  const int nt = K >> 6;
  for (int t = 0; t < nt; ++t) {
    const int cur = t & 1, nxt = cur ^ 1;
    if (t + 1 < nt) STAGE_T(nxt, (t + 1) * 64)
#pragma unroll
    for (int kk = 0; kk < 2; ++kk) {
      s16x8 Areg[MF], Breg[NF];
#pragma unroll
      for (int m = 0; m < MF; ++m)
        Areg[m] = *(const s16x8*)(Asb + cur * BM * 64 +
                                  (wr2 * (BM / 2) + m * 16 + l15) * 64 +
                                  ((((kk << 2) | l16) ^ xm) << 3));
#pragma unroll
      for (int n = 0; n < NF; ++n)
        Breg[n] = *(const s16x8*)(Bsb + cur * BN * 64 +
                                  (wc2 * (BN / 4) + n * 16 + l15) * 64 +
                                  ((((kk << 2) | l16) ^ xm) << 3));
      __builtin_amdgcn_s_setprio(1);
#pragma unroll
      for (int m = 0; m < MF; ++m)
#pragma unroll
        for (int n = 0; n < NF; ++n)
          acc[m][n] = __builtin_amdgcn_mfma_f32_16x16x32_bf16(
              Areg[m], Breg[n], acc[m][n], 0, 0, 0);
      __builtin_amdgcn_s_setprio(0);
    }
    asm volatile("s_waitcnt vmcnt(0)" ::: "memory");
    __builtin_amdgcn_s_barrier();
  }
#undef STAGE_T

  if constexpr (EPI == 0) {
    // bf16 C write (small output, GEMM1)
#pragma unroll
    for (int m = 0; m < MF; ++m) {
      int row0 = bi * BM + wr2 * (BM / 2) + m * 16 + 4 * l16;
#pragma unroll
      for (int n = 0; n < NF; ++n) {
        int col = bj * BN + wc2 * (BN / 4) + n * 16 + l15;
#pragma unroll
        for (int r = 0; r < 4; ++r)
          Cb[(size_t)(row0 + r) * ldc + col] = f2bf(acc[m][n][r]);
      }
    }
  } else {
    // coalesced epilogue: acc -> LDS (f32 128x128) -> f32x4 streaming stores
    __syncthreads();
    float* Cf = (float*)smem;
#pragma unroll
    for (int m = 0; m < MF; ++m) {
      int lr0 = wr2 * 64 + m * 16 + l16 * 4;
#pragma unroll
      for (int n = 0; n < NF; ++n) {
        int lc = wc2 * 32 + n * 16 + l15;
#pragma unroll
        for (int r = 0; r < 4; ++r)
          Cf[(lr0 + r) * 128 + lc] = acc[m][n][r];
      }
    }
    __syncthreads();
    const int mf = *mflag;
    const int r0 = tid >> 5, c0 = (tid & 31) << 2;
#pragma unroll
    for (int p = 0; p < 8; ++p) {
      int lr = p * 16 + r0;
      int row = bi * BM + lr;
      int colb = bj * BN + c0;
      f32x4 v4 = *(const f32x4*)&Cf[lr * 128 + c0];
      f32x4 rr = *(const f32x4*)&linr[colb];
      float ll = linl[row];
      size_t idx = (size_t)row * NTOK + colb;
      f32x4 o, sc;
      if (mf) {
        const unsigned char* mp = (const unsigned char*)mask + idx;
#pragma unroll
        for (int e = 0; e < 4; ++e) {
          float v = v4[e] + ll + rr[e];
          v = v > 0.f ? v : 0.f;
          o[e] = v; sc[e] = mp[e] ? v : 0.f;
        }
      } else {
        const int* mp = (const int*)mask + idx;
#pragma unroll
        for (int e = 0; e < 4; ++e) {
          float v = v4[e] + ll + rr[e];
          v = v > 0.f ? v : 0.f;
          o[e] = v; sc[e] = mp[e] ? v : 0.f;
        }
      }
      *(f32x4*)&xout[idx] = o;
      *(f32x4*)&scores[idx] = sc;
    }
  }
}

extern "C" void kernel_launch(void* const* d_in, const int* in_sizes, int n_in,
                              void* d_out, int out_size, void* d_ws, size_t ws_size,
                              hipStream_t stream) {
  const float* x_l    = (const float*)d_in[0];
  const float* x_r    = (const float*)d_in[1];
  const void*  maskp  = (const void*)d_in[2];
  const float* matrix = (const float*)d_in[3];
  const float* bias   = (const float*)d_in[4];
  const float* wl     = (const float*)d_in[5];
  const float* bl     = (const float*)d_in[6];
  const float* wr     = (const float*)d_in[7];
  const float* br     = (const float*)d_in[8];

  unsigned short* XLb = (unsigned short*)d_ws;
  unsigned short* XRb = XLb + (size_t)NTOK * DDIM;
  unsigned short* XMb = XRb + (size_t)NTOK * DDIM;
  unsigned short* Mtb = XMb + (size_t)NTOK * DDIM;
  float* lin_l = (float*)(Mtb + (size_t)DDIM * DDIM);
  float* lin_r = lin_l + NTOK;
  int* mflag = (int*)(lin_r + NTOK);

  float* scores = (float*)d_out;
  float* xout = scores + (size_t)NTOK * NTOK;

  convlin_k<<<NTOK / 4, 256, 0, stream>>>(x_l, wl, bl, bias, XLb, lin_l);
  convlin_k<<<NTOK / 4, 256, 0, stream>>>(x_r, wr, br, nullptr, XRb, lin_r);
  transpose_bf16_k<<<dim3(32, 32), dim3(32, 8), 0, stream>>>(matrix, Mtb);
  detect_mask_k<<<1, 256, 0, stream>>>((const unsigned char*)maskp, mflag);

  gemm_db_k<0, 64, 128, 8><<<512, 512, 0, stream>>>(
      XLb, Mtb, DDIM, DDIM, XMb,
      nullptr, nullptr, nullptr, nullptr, nullptr, nullptr);

  gemm_db_k<1, 128, 128, 32><<<1024, 512, 0, stream>>>(
      XMb, XRb, DDIM, NTOK, nullptr,
      lin_l, lin_r, maskp, mflag, scores, xout);
}